// Round 10
// baseline (127.567 us; speedup 1.0000x reference)
//
#include <hip/hip_runtime.h>

typedef __attribute__((ext_vector_type(8))) short bf16x8;
typedef __attribute__((ext_vector_type(4))) float f32x4;

namespace {

constexpr int B = 32, T = 128, V = 128, F = 64, O = 64;
constexpr int TPB = 16;   // 16 t's = 8 pairs per block; grid = (8, 32) = 256 blocks = 1/CU

// ws layout (bytes):
//   [acat_f bf16: B * (8 ks * 8 r2 * 64 lane) frags * 16B = 2 MiB]   fragment-major Acat
//   [tht_f  bf16: (2 ks * 12 nf * 64 lane) frags * 16B = 24 KiB]     fragment-major ThT
//   [ldg    f32 : B*V = 16 KiB]
constexpr size_t WS_THT_OFF = (size_t)B * 64 * 64 * 8 * 2;   // 2 MiB
constexpr size_t WS_LDG_OFF = WS_THT_OFF + 1536 * 8 * 2;     // +24 KiB

__device__ inline unsigned short f2bf(float f) {
    unsigned u = __builtin_bit_cast(unsigned, f);
    u += 0x7FFFu + ((u >> 16) & 1u);
    return (unsigned short)(u >> 16);
}

// ---------------- prep: fragment-major Acat/ThT, ldiag (unchanged) ----------------
__global__ __launch_bounds__(256) void prep(const float* __restrict__ W,
                                            const float* __restrict__ Theta,
                                            unsigned short* __restrict__ acat_f,
                                            unsigned short* __restrict__ tht_f,
                                            float* __restrict__ ldg) {
    const int tid = threadIdx.x;
    if (blockIdx.x == B) {
        for (int i = 0; i < 6; ++i) {
            int fi = tid + i * 256;                 // [0,1536)
            int ks = fi / 768, rem = fi % 768;
            int nf = rem >> 6, lane = rem & 63;
            int n = nf * 16 + (lane & 15);
            int f0 = ks * 32 + (lane >> 4) * 8;
            unsigned short vals[8];
#pragma unroll
            for (int j = 0; j < 8; ++j) {
                int f = f0 + j;
                float v;
                if (n < 64)       v = Theta[f * 64 + n] - Theta[2 * 4096 + f * 64 + n];
                else if (n < 128) v = Theta[4096 + f * 64 + (n - 64)];
                else              v = Theta[2 * 4096 + f * 64 + (n - 128)];
                vals[j] = f2bf(v);
            }
            *(bf16x8*)(tht_f + (size_t)fi * 8) = *(bf16x8*)vals;
        }
        return;
    }
    const int b = blockIdx.x;
    const float* Wb = W + (size_t)b * V * V;
    __shared__ float Wl[V][V + 1];
    for (int i = 0; i < V * V / 256; ++i) {
        int idx = tid + i * 256;
        Wl[idx >> 7][idx & 127] = Wb[idx];
    }
    __syncthreads();
    if (tid < V) {
        float s = 0.f;
        for (int i = 0; i < V; ++i) s += Wl[i][tid];       // deg[u] = sum_i W[i][u]
        ldg[b * V + tid] = s - 1.0f - Wl[tid][tid];        // ldiag
    }
    unsigned short* ab_f = acat_f + (size_t)b * 32768;
    for (int i = 0; i < 16; ++i) {
        int fi = tid + i * 256;                    // [0,4096)
        int ks = fi >> 9, rem = fi & 511;
        int r2 = rem >> 6, lane = rem & 63;
        int u = r2 * 16 + (lane & 15);
        int kv0 = ks * 32 + (lane >> 4) * 8;
        unsigned short vals[8];
#pragma unroll
        for (int j = 0; j < 8; ++j) {
            int kv = kv0 + j, v = kv & 127;
            float wv = Wl[v][u];
            float val = (v == u) ? 0.f : ((kv < 128) ? -wv : 2.f * wv * wv);
            vals[j] = f2bf(val);
        }
        *(bf16x8*)(ab_f + (size_t)fi * 8) = *(bf16x8*)vals;
    }
}

// ---------------- main: 512 threads per (b, 16 t's); TBATCH=2, 32 rows/wave ----------------
__global__ __launch_bounds__(512, 2) void graph_conv_main(
    const float* __restrict__ x, const unsigned short* __restrict__ acat_f,
    const unsigned short* __restrict__ tht_f, const float* __restrict__ ldg,
    float* __restrict__ out) {
    const int t0 = blockIdx.x * TPB, b = blockIdx.y;
    const int tid = threadIdx.x;                 // 0..511
    const int lane = tid & 63, w = tid >> 6;
    const int q = w & 3;                         // row-slab [32q, 32q+32)
    const int p = w >> 2;                        // t-parity within pair
    const int lr = lane & 15, lg = lane >> 4;

    __shared__ __align__(16) unsigned short tht_s[12288];      // 24 KB
    __shared__ __align__(16) unsigned short xbuf[2][2][8192];  // 64 KB: [dbuf][p][128x64 bf16]
    __shared__ __align__(16) unsigned short zc1[2][8192];      // 32 KB: [p][o=64][v=128]  (correctly sized now)
    __shared__ __align__(16) unsigned short zc2[2][8192];      // 32 KB
    // total 152 KB -> 1 block/CU

    const float* xb = x + ((size_t)(b * T + t0)) * (V * F);

    // ---- stage tht_s via global_load_lds (linear both sides) ----
#pragma unroll
    for (int i = 0; i < 3; ++i) {
        int c = tid + i * 512;               // 1536 chunks of 16B
        __builtin_amdgcn_global_load_lds(
            (const __attribute__((address_space(1))) void*)(tht_f + c * 8),
            (__attribute__((address_space(3))) void*)(tht_s + c * 8), 16, 0, 0);
    }

    // ---- Acat fragments for this wave's 32 u-rows (t-invariant): 16 frags = 64 VGPR ----
    bf16x8 af_r[2][8];
#pragma unroll
    for (int ks = 0; ks < 8; ++ks)
#pragma unroll
        for (int uf = 0; uf < 2; ++uf)
            af_r[uf][ks] = *(const bf16x8*)(acat_f +
                (((size_t)b * 64 + ks * 8 + 2 * q + uf) * 64 + lane) * 8);

    // ---- ldiag fragments for rows 32q+16vf+lg*4 ----
    const float* ldb = ldg + b * V;
    f32x4 ldv[2], ld2v[2];
#pragma unroll
    for (int vf = 0; vf < 2; ++vf) {
        ldv[vf] = *(const f32x4*)(ldb + 32 * q + 16 * vf + lg * 4);
        ld2v[vf] = 2.0f * ldv[vf] * ldv[vf];
    }

    // per-thread x prefetch: 8 float4 = one PAIR of t-tiles across the block
    float4 pf[8];
    auto load_pf = [&](int pr) {
        const float4* s0 = (const float4*)(xb + (size_t)(2 * pr) * (V * F));
        const float4* s1 = (const float4*)(xb + (size_t)(2 * pr + 1) * (V * F));
#pragma unroll
        for (int i = 0; i < 4; ++i) pf[i] = s0[tid + i * 512];
#pragma unroll
        for (int i = 0; i < 4; ++i) pf[4 + i] = s1[tid + i * 512];
    };
    auto store_pf = [&](int buf) {
#pragma unroll
        for (int i = 0; i < 8; ++i) {
            int pp = i >> 2;
            int f4 = tid + (i & 3) * 512;        // float4 idx in 128x64 tile
            int row = f4 >> 4, c4 = f4 & 15;
            uint2 qq;
            qq.x = f2bf(pf[i].x) | ((unsigned)f2bf(pf[i].y) << 16);
            qq.y = f2bf(pf[i].z) | ((unsigned)f2bf(pf[i].w) << 16);
            *(uint2*)((char*)xbuf + (size_t)(buf * 2 + pp) * 16384 +
                      row * 128 + ((c4 * 8) ^ ((row & 7) << 4))) = qq;
        }
    };

    load_pf(0);
    store_pf(0);       // waits pf; also drains tht gl_lds
    __syncthreads();
    int cur = 0;

    for (int it = 0; it < TPB / 2; ++it) {
        if (it + 1 < TPB / 2) load_pf(it + 1);   // in-flight until store_pf after contraction

        // ---- xa fragments: own 32-row slab of t_p ----
        const char* xc = (const char*)xbuf + (size_t)(cur * 2 + p) * 16384;
        bf16x8 xa[2][2];
#pragma unroll
        for (int vf = 0; vf < 2; ++vf) {
            const int row = 32 * q + 16 * vf + lr;
            const int rb = row * 128, rs = (row & 7) << 4;
#pragma unroll
            for (int ks = 0; ks < 2; ++ks)
                xa[vf][ks] = *(const bf16x8*)(xc + rb + ((ks * 64 + lg * 16) ^ rs));
        }

        f32x4 acc[2][4], z[2][4];
#pragma unroll
        for (int vf = 0; vf < 2; ++vf)
#pragma unroll
            for (int of = 0; of < 4; ++of) {
                acc[vf][of] = (f32x4){0.f, 0.f, 0.f, 0.f};
                z[vf][of] = (f32x4){0.f, 0.f, 0.f, 0.f};
            }

        // ---- part 1: Zm -> acc (nf 0..3), Z1 -> z (nf 4..7) ----
#pragma unroll
        for (int ks = 0; ks < 2; ++ks)
#pragma unroll
            for (int nf = 0; nf < 8; ++nf) {
                bf16x8 tb = *(const bf16x8*)(tht_s + ((ks * 12 + nf) * 64 + lane) * 8);
                if (nf < 4) {
                    acc[0][nf] = __builtin_amdgcn_mfma_f32_16x16x32_bf16(xa[0][ks], tb, acc[0][nf], 0, 0, 0);
                    acc[1][nf] = __builtin_amdgcn_mfma_f32_16x16x32_bf16(xa[1][ks], tb, acc[1][nf], 0, 0, 0);
                } else {
                    z[0][nf - 4] = __builtin_amdgcn_mfma_f32_16x16x32_bf16(xa[0][ks], tb, z[0][nf - 4], 0, 0, 0);
                    z[1][nf - 4] = __builtin_amdgcn_mfma_f32_16x16x32_bf16(xa[1][ks], tb, z[1][nf - 4], 0, 0, 0);
                }
            }

        // ---- diag(Z1) + write Z1 -> zc1[p]; reuse z regs ----
        char* z1p = (char*)zc1 + (size_t)p * 16384;
        char* z2p = (char*)zc2 + (size_t)p * 16384;
#pragma unroll
        for (int vf = 0; vf < 2; ++vf) {
            const int vcol = 32 * q + 16 * vf + lg * 4;
#pragma unroll
            for (int of = 0; of < 4; ++of) {
                acc[vf][of] += ldv[vf] * z[vf][of];
                const int rowz = of * 16 + lr;
                f32x4 zv = z[vf][of];
                uint2 qq;
                qq.x = f2bf(zv[0]) | ((unsigned)f2bf(zv[1]) << 16);
                qq.y = f2bf(zv[2]) | ((unsigned)f2bf(zv[3]) << 16);
                *(uint2*)(z1p + rowz * 256 + ((vcol * 2) ^ ((rowz & 7) << 4))) = qq;
                z[vf][of] = (f32x4){0.f, 0.f, 0.f, 0.f};
            }
        }

        // ---- part 2: Z2 (nf 8..11) ----
#pragma unroll
        for (int ks = 0; ks < 2; ++ks)
#pragma unroll
            for (int nf = 0; nf < 4; ++nf) {
                bf16x8 tb = *(const bf16x8*)(tht_s + ((ks * 12 + 8 + nf) * 64 + lane) * 8);
                z[0][nf] = __builtin_amdgcn_mfma_f32_16x16x32_bf16(xa[0][ks], tb, z[0][nf], 0, 0, 0);
                z[1][nf] = __builtin_amdgcn_mfma_f32_16x16x32_bf16(xa[1][ks], tb, z[1][nf], 0, 0, 0);
            }

        // ---- diag(Z2) + write Z2 -> zc2[p] ----
#pragma unroll
        for (int vf = 0; vf < 2; ++vf) {
            const int vcol = 32 * q + 16 * vf + lg * 4;
#pragma unroll
            for (int of = 0; of < 4; ++of) {
                acc[vf][of] += ld2v[vf] * z[vf][of];
                const int rowz = of * 16 + lr;
                f32x4 zv = z[vf][of];
                uint2 qq;
                qq.x = f2bf(zv[0]) | ((unsigned)f2bf(zv[1]) << 16);
                qq.y = f2bf(zv[2]) | ((unsigned)f2bf(zv[3]) << 16);
                *(uint2*)(z2p + rowz * 256 + ((vcol * 2) ^ ((rowz & 7) << 4))) = qq;
            }
        }

        __syncthreads();   // B: zc[p] visible

        // ---- contraction: acc += Acat[u,0:256] @ [Z1;Z2]; af from regs, 2 MFMAs per zb read ----
#pragma unroll
        for (int ks = 0; ks < 8; ++ks) {
            const char* zsrc = (ks < 4) ? (const char*)z1p : (const char*)z2p;
            const int kcol = (ks & 3) * 64 + lg * 16;
#pragma unroll
            for (int of = 0; of < 4; ++of) {
                const int rowz = of * 16 + lr;
                bf16x8 zb = *(const bf16x8*)(zsrc + rowz * 256 + (kcol ^ ((rowz & 7) << 4)));
                acc[0][of] = __builtin_amdgcn_mfma_f32_16x16x32_bf16(af_r[0][ks], zb, acc[0][of], 0, 0, 0);
                acc[1][of] = __builtin_amdgcn_mfma_f32_16x16x32_bf16(af_r[1][ks], zb, acc[1][of], 0, 0, 0);
            }
        }

        if (it + 1 < TPB / 2) store_pf(cur ^ 1);   // pf consumed post-compute

        // ---- epilogue: relu + store t = t0 + 2*it + p ----
        float* obt = out + ((size_t)(b * T + t0 + 2 * it + p)) * (V * O);
#pragma unroll
        for (int vf = 0; vf < 2; ++vf)
#pragma unroll
            for (int of = 0; of < 4; ++of)
#pragma unroll
                for (int j = 0; j < 4; ++j) {
                    const int u = 32 * q + 16 * vf + lg * 4 + j;
                    const int o = of * 16 + lr;
                    const float r = acc[vf][of][j];
                    obt[u * 64 + o] = r > 0.f ? r : 0.f;
                }

        __syncthreads();   // C: zc reads done; xbuf[cur^1] ready
        cur ^= 1;
    }
}

}  // namespace

extern "C" void kernel_launch(void* const* d_in, const int* in_sizes, int n_in,
                              void* d_out, int out_size, void* d_ws, size_t ws_size,
                              hipStream_t stream) {
    const float* x = (const float*)d_in[0];      // (B,T,V,F)
    const float* W = (const float*)d_in[1];      // (B,V,V)
    const float* Theta = (const float*)d_in[2];  // (3,F,O)
    float* outp = (float*)d_out;                 // (B,T,V,O)

    unsigned short* acat_f = (unsigned short*)d_ws;
    unsigned short* tht_f = (unsigned short*)((char*)d_ws + WS_THT_OFF);
    float* ldg = (float*)((char*)d_ws + WS_LDG_OFF);

    prep<<<B + 1, 256, 0, stream>>>(W, Theta, acat_f, tht_f, ldg);
    graph_conv_main<<<dim3(T / TPB, B), 512, 0, stream>>>(x, acat_f, tht_f, ldg, outp);
}

// Round 11
// 87.942 us; speedup vs baseline: 1.4506x; 1.4506x over previous
//
#include <hip/hip_runtime.h>

typedef __attribute__((ext_vector_type(8))) short bf16x8;
typedef __attribute__((ext_vector_type(4))) float f32x4;

namespace {

constexpr int B = 32, T = 128, V = 128, F = 64, O = 64;
constexpr int TPB = 16;   // t-tiles per block; grid = (8, 32) = 256 blocks = 1/CU

// ws layout (bytes):
//   [acat_f bf16: B * (8 ks * 8 r2 * 64 lane) frags * 16B = 2 MiB]   fragment-major Acat
//   [tht_f  bf16: (2 ks * 12 nf * 64 lane) frags * 16B = 24 KiB]     fragment-major ThT
//   [ldg    f32 : B*V = 16 KiB]
constexpr size_t WS_THT_OFF = (size_t)B * 64 * 64 * 8 * 2;   // 2 MiB
constexpr size_t WS_LDG_OFF = WS_THT_OFF + 1536 * 8 * 2;     // +24 KiB

__device__ inline unsigned short f2bf(float f) {
    unsigned u = __builtin_bit_cast(unsigned, f);
    u += 0x7FFFu + ((u >> 16) & 1u);
    return (unsigned short)(u >> 16);
}

// ---------------- prep: fragment-major Acat/ThT, ldiag (unchanged) ----------------
__global__ __launch_bounds__(256) void prep(const float* __restrict__ W,
                                            const float* __restrict__ Theta,
                                            unsigned short* __restrict__ acat_f,
                                            unsigned short* __restrict__ tht_f,
                                            float* __restrict__ ldg) {
    const int tid = threadIdx.x;
    if (blockIdx.x == B) {
        for (int i = 0; i < 6; ++i) {
            int fi = tid + i * 256;                 // [0,1536)
            int ks = fi / 768, rem = fi % 768;
            int nf = rem >> 6, lane = rem & 63;
            int n = nf * 16 + (lane & 15);
            int f0 = ks * 32 + (lane >> 4) * 8;
            unsigned short vals[8];
#pragma unroll
            for (int j = 0; j < 8; ++j) {
                int f = f0 + j;
                float v;
                if (n < 64)       v = Theta[f * 64 + n] - Theta[2 * 4096 + f * 64 + n];
                else if (n < 128) v = Theta[4096 + f * 64 + (n - 64)];
                else              v = Theta[2 * 4096 + f * 64 + (n - 128)];
                vals[j] = f2bf(v);
            }
            *(bf16x8*)(tht_f + (size_t)fi * 8) = *(bf16x8*)vals;
        }
        return;
    }
    const int b = blockIdx.x;
    const float* Wb = W + (size_t)b * V * V;
    __shared__ float Wl[V][V + 1];
    for (int i = 0; i < V * V / 256; ++i) {
        int idx = tid + i * 256;
        Wl[idx >> 7][idx & 127] = Wb[idx];
    }
    __syncthreads();
    if (tid < V) {
        float s = 0.f;
        for (int i = 0; i < V; ++i) s += Wl[i][tid];       // deg[u] = sum_i W[i][u]
        ldg[b * V + tid] = s - 1.0f - Wl[tid][tid];        // ldiag
    }
    unsigned short* ab_f = acat_f + (size_t)b * 32768;
    for (int i = 0; i < 16; ++i) {
        int fi = tid + i * 256;                    // [0,4096)
        int ks = fi >> 9, rem = fi & 511;
        int r2 = rem >> 6, lane = rem & 63;
        int u = r2 * 16 + (lane & 15);
        int kv0 = ks * 32 + (lane >> 4) * 8;
        unsigned short vals[8];
#pragma unroll
        for (int j = 0; j < 8; ++j) {
            int kv = kv0 + j, v = kv & 127;
            float wv = Wl[v][u];
            float val = (v == u) ? 0.f : ((kv < 128) ? -wv : 2.f * wv * wv);
            vals[j] = f2bf(val);
        }
        *(bf16x8*)(ab_f + (size_t)fi * 8) = *(bf16x8*)vals;
    }
}

// ---------------- main: counted-vmcnt pipeline, raw barriers, wave-local x staging ----------------
__global__ __launch_bounds__(512, 2) void graph_conv_main(
    const float* __restrict__ x, const unsigned short* __restrict__ acat_f,
    const unsigned short* __restrict__ tht_f, const float* __restrict__ ldg,
    float* __restrict__ out) {
    const int t0 = blockIdx.x * TPB, b = blockIdx.y;
    const int tid = threadIdx.x;                 // 0..511
    const int lane = tid & 63, w = tid >> 6;     // 8 waves; wave w owns rows [16w, 16w+16)
    const int lr = lane & 15, lg = lane >> 4;

    __shared__ __align__(16) unsigned short tht_s[12288];   // 24 KB
    __shared__ __align__(16) float xbuf[2][V * F];          // 64 KB fp32, src-side swizzle
    __shared__ __align__(16) unsigned short zc1[8192];      // 16 KB [o=64][v=128] (FIXED size)
    __shared__ __align__(16) unsigned short zc2[8192];      // 16 KB
    // total 120 KB -> 1 block/CU

    const float* xb = x + ((size_t)(b * T + t0)) * (V * F);

    // ---- af_r + ldiag loads (compiler-managed), then force complete before manual vmcnt bookkeeping ----
    bf16x8 af_r[8];
#pragma unroll
    for (int ks = 0; ks < 8; ++ks)
        af_r[ks] = *(const bf16x8*)(acat_f + (((size_t)b * 64 + ks * 8 + w) * 64 + lane) * 8);
    const f32x4 ldv = *(const f32x4*)(ldg + b * V + 16 * w + lg * 4);
    const f32x4 ld2v = 2.0f * ldv * ldv;
    asm volatile("s_waitcnt vmcnt(0)" ::: "memory");
    __builtin_amdgcn_sched_barrier(0);

    // stage_x: wave-local slab (rows [16w,16w+16) fp32, 4 KB, 4 gl_lds), LDS dest linear,
    // inverse swizzle on the GLOBAL source: 32B slot ^= (row&7).
    auto stage_x = [&](int tt, int buf) {
        const char* src = (const char*)(xb + (size_t)tt * (V * F));
        char* lbase = (char*)&xbuf[buf][0] + w * 4096;
#pragma unroll
        for (int j = 0; j < 4; ++j) {
            int a = j * 1024 + lane * 16;        // LDS byte offset within slab
            int rloc = a >> 8;                   // local row
            int slot = (a >> 5) & 7;
            int within = a & 31;
            int row = 16 * w + rloc;
            const char* g = src + row * 256 + ((slot ^ (row & 7)) << 5) + within;
            __builtin_amdgcn_global_load_lds(
                (const __attribute__((address_space(1))) void*)g,
                (__attribute__((address_space(3))) void*)(lbase + j * 1024), 16, 0, 0);
        }
    };

    // ---- stage tht + x(t0); single full drain + barrier ----
#pragma unroll
    for (int i = 0; i < 3; ++i) {
        int c = tid + i * 512;               // 1536 chunks of 16B
        __builtin_amdgcn_global_load_lds(
            (const __attribute__((address_space(1))) void*)(tht_f + c * 8),
            (__attribute__((address_space(3))) void*)(tht_s + c * 8), 16, 0, 0);
    }
    stage_x(0, 0);
    asm volatile("s_waitcnt vmcnt(0)" ::: "memory");
    __builtin_amdgcn_sched_barrier(0);
    __builtin_amdgcn_s_barrier();
    __builtin_amdgcn_sched_barrier(0);

    int cur = 0;
    for (int tt = 0; tt < TPB; ++tt) {
        // ---- issue next tile's loads; they stay in flight the WHOLE iteration ----
        if (tt + 1 < TPB) stage_x(tt + 1, cur ^ 1);
        // wait until only the 4 just-issued gl_lds remain outstanding:
        // guarantees tile-tt loads (older) landed; prior-iter stores also retired.
        asm volatile("s_waitcnt vmcnt(4)" ::: "memory");
        __builtin_amdgcn_sched_barrier(0);

        // ---- xa fragments: fp32 from own swizzled slab, cvt -> bf16 ----
        bf16x8 xa[2];
        {
            const int row = 16 * w + lr;
            const char* rbp = (const char*)&xbuf[cur][0] + row * 256;
            const int rs = row & 7;
#pragma unroll
            for (int ks = 0; ks < 2; ++ks) {
                const char* pa = rbp + (((ks * 4 + lg) ^ rs) << 5);
                f32x4 a0 = *(const f32x4*)pa;
                f32x4 a1 = *(const f32x4*)(pa + 16);
                uint4 u;
                u.x = f2bf(a0[0]) | ((unsigned)f2bf(a0[1]) << 16);
                u.y = f2bf(a0[2]) | ((unsigned)f2bf(a0[3]) << 16);
                u.z = f2bf(a1[0]) | ((unsigned)f2bf(a1[1]) << 16);
                u.w = f2bf(a1[2]) | ((unsigned)f2bf(a1[3]) << 16);
                xa[ks] = __builtin_bit_cast(bf16x8, u);
            }
        }

        f32x4 acc[4], z[4];
#pragma unroll
        for (int of = 0; of < 4; ++of) {
            acc[of] = (f32x4){0.f, 0.f, 0.f, 0.f};
            z[of] = (f32x4){0.f, 0.f, 0.f, 0.f};
        }

        // ---- part 1: Zm -> acc (nf 0..3), Z1 -> z (nf 4..7); tb from LDS ----
#pragma unroll
        for (int ks = 0; ks < 2; ++ks)
#pragma unroll
            for (int nf = 0; nf < 8; ++nf) {
                bf16x8 tb = *(const bf16x8*)(tht_s + ((ks * 12 + nf) * 64 + lane) * 8);
                if (nf < 4) acc[nf] = __builtin_amdgcn_mfma_f32_16x16x32_bf16(xa[ks], tb, acc[nf], 0, 0, 0);
                else        z[nf - 4] = __builtin_amdgcn_mfma_f32_16x16x32_bf16(xa[ks], tb, z[nf - 4], 0, 0, 0);
            }

        // ---- diag(Z1) + write Z1^T -> zc1; reuse z regs ----
        {
            const int vcol = 16 * w + lg * 4;
#pragma unroll
            for (int of = 0; of < 4; ++of) {
                acc[of] += ldv * z[of];
                const int rowz = of * 16 + lr;
                f32x4 zv = z[of];
                uint2 q;
                q.x = f2bf(zv[0]) | ((unsigned)f2bf(zv[1]) << 16);
                q.y = f2bf(zv[2]) | ((unsigned)f2bf(zv[3]) << 16);
                *(uint2*)((char*)zc1 + rowz * 256 + ((vcol * 2) ^ ((rowz & 7) << 4))) = q;
                z[of] = (f32x4){0.f, 0.f, 0.f, 0.f};
            }
        }

        // ---- part 2: Z2 (nf 8..11) ----
#pragma unroll
        for (int ks = 0; ks < 2; ++ks)
#pragma unroll
            for (int nf = 0; nf < 4; ++nf) {
                bf16x8 tb = *(const bf16x8*)(tht_s + ((ks * 12 + 8 + nf) * 64 + lane) * 8);
                z[nf] = __builtin_amdgcn_mfma_f32_16x16x32_bf16(xa[ks], tb, z[nf], 0, 0, 0);
            }

        // ---- diag(Z2) + write Z2^T -> zc2 ----
        {
            const int vcol = 16 * w + lg * 4;
#pragma unroll
            for (int of = 0; of < 4; ++of) {
                acc[of] += ld2v * z[of];
                const int rowz = of * 16 + lr;
                f32x4 zv = z[of];
                uint2 q;
                q.x = f2bf(zv[0]) | ((unsigned)f2bf(zv[1]) << 16);
                q.y = f2bf(zv[2]) | ((unsigned)f2bf(zv[3]) << 16);
                *(uint2*)((char*)zc2 + rowz * 256 + ((vcol * 2) ^ ((rowz & 7) << 4))) = q;
            }
        }

        // ---- barrier WITHOUT vmcnt drain: only LDS ordering ----
        asm volatile("s_waitcnt lgkmcnt(0)" ::: "memory");
        __builtin_amdgcn_sched_barrier(0);
        __builtin_amdgcn_s_barrier();
        __builtin_amdgcn_sched_barrier(0);

        // ---- contraction: acc += Acat[u,0:256] @ [Z1;Z2]; af from regs ----
#pragma unroll
        for (int ks = 0; ks < 8; ++ks) {
            const char* zsrc = (ks < 4) ? (const char*)zc1 : (const char*)zc2;
            const int kcol = (ks & 3) * 64 + lg * 16;
#pragma unroll
            for (int of = 0; of < 4; ++of) {
                const int rowz = of * 16 + lr;
                bf16x8 zb = *(const bf16x8*)(zsrc + rowz * 256 + (kcol ^ ((rowz & 7) << 4)));
                acc[of] = __builtin_amdgcn_mfma_f32_16x16x32_bf16(af_r[ks], zb, acc[of], 0, 0, 0);
            }
        }

        // ---- epilogue: relu + store t = t0+tt (stores stay in flight past the barrier) ----
        float* obt = out + ((size_t)(b * T + t0 + tt)) * (V * O);
#pragma unroll
        for (int of = 0; of < 4; ++of)
#pragma unroll
            for (int j = 0; j < 4; ++j) {
                const int u = 16 * w + lg * 4 + j;
                const int o = of * 16 + lr;
                const float r = acc[of][j];
                obt[u * 64 + o] = r > 0.f ? r : 0.f;
            }

        // ---- end barrier, again lgkm-only: zc reusable next iter ----
        asm volatile("s_waitcnt lgkmcnt(0)" ::: "memory");
        __builtin_amdgcn_sched_barrier(0);
        __builtin_amdgcn_s_barrier();
        __builtin_amdgcn_sched_barrier(0);
        cur ^= 1;
    }
}

}  // namespace

extern "C" void kernel_launch(void* const* d_in, const int* in_sizes, int n_in,
                              void* d_out, int out_size, void* d_ws, size_t ws_size,
                              hipStream_t stream) {
    const float* x = (const float*)d_in[0];      // (B,T,V,F)
    const float* W = (const float*)d_in[1];      // (B,V,V)
    const float* Theta = (const float*)d_in[2];  // (3,F,O)
    float* outp = (float*)d_out;                 // (B,T,V,O)

    unsigned short* acat_f = (unsigned short*)d_ws;
    unsigned short* tht_f = (unsigned short*)((char*)d_ws + WS_THT_OFF);
    float* ldg = (float*)((char*)d_ws + WS_LDG_OFF);

    prep<<<B + 1, 256, 0, stream>>>(W, Theta, acat_f, tht_f, ldg);
    graph_conv_main<<<dim3(T / TPB, B), 512, 0, stream>>>(x, acat_f, tht_f, ldg, outp);
}